// Round 10
// baseline (356.057 us; speedup 1.0000x reference)
//
#include <hip/hip_runtime.h>
#include <hip/hip_bf16.h>

// GraphConv on MI355X — atomic-built fixed-stride CSR (96 slots/node),
// in-register per-64-tile src sort (canonicalizes order -> determinism),
// batch-per-XCD plane split in aggregate.
//   y[b][n][:] = bf16(nw[n] * (inputs[b,n] @ W))    (MFMA 16x16x32 bf16)
//   out[b,n,:] = nw[n]*(y[b][n] + sum_{e:dst=n} y[b][src_e]) + bias
// R18: counting-sort chain (phist -> reduce -> scatter, 3 launches + 25.6MB
// hist traffic) REPLACED by one global-atomic scatter. Aggregate's per-node
// bitonic sort makes the accumulation order independent of CSR arrival order
// for deg <= 64 (P(deg>64) ~ 2e-7/node, Poisson(32)) -> deterministic result.
// node_w arrays eliminated: gemm/aggregate compute rsqrt(cntS[n]+1) inline.
// Launches 5 -> 4 (memset + scatter + gemm + aggregate); ~10us/launch measured
// (R2->R3: 24us for sort kernel+gap; R8->R9: 9us for offsets kernel+gap).

#define NN 50000
#define EE 1600000
#define DD 128
#define BB 2
#define SLOTS 96      // fixed csr row stride (u16 elems); max deg ~60 << 96

typedef __attribute__((ext_vector_type(8))) short short8;
typedef __attribute__((ext_vector_type(8))) unsigned short ushort8v;
typedef __attribute__((ext_vector_type(4))) float floatx4;
typedef __attribute__((ext_vector_type(2))) float floatx2;
typedef __attribute__((ext_vector_type(4))) unsigned int uintx4;

__device__ inline unsigned short f2bf(float f) {  // RNE fp32 -> bf16 bits
    unsigned u = __float_as_uint(f);
    unsigned r = u + 0x7fffu + ((u >> 16) & 1u);
    return (unsigned short)(r >> 16);
}
__device__ inline float bf2f(unsigned short h) {
    return __uint_as_float(((unsigned)h) << 16);
}

// ---------------- atomic scatter into fixed-stride CSR + degree counters ----------------
// pos = atomicAdd(cntD[dst]) -> csr[dst*96+pos] = src; cntS[src]++ for node_w.
// Arrival order is nondeterministic; aggregate's per-node bitonic sort by src
// value canonicalizes it (deg <= 64 -> bit-identical output).
__global__ __launch_bounds__(256) void scatter_atomic_kernel(
    const int4* __restrict__ adj2, unsigned int* __restrict__ cntD,
    unsigned int* __restrict__ cntS, unsigned short* __restrict__ csr_src) {
    int i = blockIdx.x * blockDim.x + threadIdx.x;  // pair index, grid == EE/2
    int4 two = adj2[i];  // edges (x,y) and (z,w): (src,dst)
    unsigned pA = atomicAdd(&cntD[two.y], 1u);
    csr_src[two.y * SLOTS + pA] = (unsigned short)two.x;
    atomicAdd(&cntS[two.x], 1u);
    unsigned pB = atomicAdd(&cntD[two.w], 1u);
    csr_src[two.w * SLOTS + pB] = (unsigned short)two.z;
    atomicAdd(&cntS[two.z], 1u);
}

// ---------------- y = bf16(nw * (inputs @ W)), plane layout [b][n][128] ----------------
// nw computed inline from src-degree counters (no node_w array).
#define WT_STRIDE 136
__global__ __launch_bounds__(1024) void gemm_mfma_kernel(const float* __restrict__ in,
                                                         const float* __restrict__ W,
                                                         const unsigned int* __restrict__ cntS,
                                                         unsigned short* __restrict__ y,
                                                         int total_rows) {
    __shared__ unsigned short wt[128 * WT_STRIDE];  // W^T as bf16, ~34 KB
    for (int i = threadIdx.x; i < 128 * 128; i += 1024) {
        int d = i >> 7, o = i & 127;
        wt[o * WT_STRIDE + d] = f2bf(W[i]);
    }
    __syncthreads();

    int wave = threadIdx.x >> 6;  // 0..15
    int lane = threadIdx.x & 63;
    int m = lane & 15;
    int quad = lane >> 4;
    int rt = (blockIdx.x * 16 + wave) * 16;
    if (rt >= total_rows) return;

    short8 a[4];
    const float* arow = in + (size_t)(rt + m) * 128;
#pragma unroll
    for (int kt = 0; kt < 4; ++kt) {
        int k0 = kt * 32 + quad * 8;
        float4 f0 = *(const float4*)(arow + k0);
        float4 f1 = *(const float4*)(arow + k0 + 4);
        short8 av;
        av[0] = (short)f2bf(f0.x); av[1] = (short)f2bf(f0.y);
        av[2] = (short)f2bf(f0.z); av[3] = (short)f2bf(f0.w);
        av[4] = (short)f2bf(f1.x); av[5] = (short)f2bf(f1.y);
        av[6] = (short)f2bf(f1.z); av[7] = (short)f2bf(f1.w);
        a[kt] = av;
    }

    float nw[4];
#pragma unroll
    for (int r = 0; r < 4; ++r) {
        int row = rt + quad * 4 + r;
        int n = row - (row >= NN ? NN : 0);
        nw[r] = rsqrtf((float)cntS[n] + 1.0f);
    }

#pragma unroll
    for (int ct = 0; ct < 8; ++ct) {
        floatx4 acc = {0.f, 0.f, 0.f, 0.f};
#pragma unroll
        for (int kt = 0; kt < 4; ++kt) {
            const short8* bp =
                (const short8*)&wt[(ct * 16 + m) * WT_STRIDE + kt * 32 + quad * 8];
            acc = __builtin_amdgcn_mfma_f32_16x16x32_bf16(a[kt], *bp, acc, 0, 0, 0);
        }
        int col = ct * 16 + m;
#pragma unroll
        for (int r = 0; r < 4; ++r) {
            int row = rt + quad * 4 + r;
            y[(size_t)row * 128 + col] = f2bf(nw[r] * acc[r]);
        }
    }
}

// ---------------- aggregation: 1 wave per (node,batch), in-register sorted gathers ----------------
// blk%8 -> XCD: batch = (blk%8)>>2 -> each XCD sweeps ONE 12.8MB y-plane
// (R6: dropping this costs +59MB FETCH, +7us). Bitonic sorts each 64-tile;
// k=64 merge class skipped when mm<=32 (R7: -6.6us). Fixed-stride csr:
// start = n*SLOTS (scalar). 4 dwordx4 gathers in flight; nt stores;
// launch_bounds(256,8) keeps VGPR low -> 8 waves/SIMD.
__global__ __launch_bounds__(256, 8) void aggregate_kernel(
    const unsigned short* __restrict__ yb, const unsigned short* __restrict__ csr_src,
    const unsigned int* __restrict__ cntD, const unsigned int* __restrict__ cntS,
    const float* __restrict__ bias, float* __restrict__ out) {
    int wave = threadIdx.x >> 6;
    int lane = threadIdx.x & 63;
    unsigned blk = blockIdx.x;                     // [0, 25000)
    int xcd = (int)(blk & 7u);
    int bg = xcd >> 2;                             // batch
    int nbid = (int)(blk >> 3) * 4 + (xcd & 3);    // [0, 12500)
    int n = nbid * 4 + wave;

    int g = lane >> 4;
    int c8 = lane & 15;
    int c16 = c8 * 16;
    const char* ybase = (const char*)yb + (size_t)bg * (NN * 128 * 2);

    int start = n * SLOTS;                         // wave-uniform, scalar
    int cnt = __builtin_amdgcn_readfirstlane((int)cntD[n]);

    floatx2 acc2[4];
#pragma unroll
    for (int k = 0; k < 4; ++k) acc2[k] = (floatx2){0.f, 0.f};

#define ACC16(LD)                                                       \
    {                                                                   \
        _Pragma("unroll") for (int d = 0; d < 4; ++d) {                 \
            floatx2 v2;                                                 \
            v2.x = __uint_as_float((LD)[d] << 16);                      \
            v2.y = __uint_as_float((LD)[d] & 0xffff0000u);              \
            acc2[d] += v2;                                              \
        }                                                               \
    }

    for (int base = 0; base < cnt; base += 64) {
        int mm = cnt - base; if (mm > 64) mm = 64;
        // ---- in-register bitonic sort (k<=32 classes always) ----
        int v = (lane < mm) ? (int)csr_src[start + base + lane] : 0x7fffffff;
#pragma unroll
        for (int k = 2; k <= 32; k <<= 1) {
#pragma unroll
            for (int j = k >> 1; j > 0; j >>= 1) {
                int other = __shfl_xor(v, j);
                bool lower = (lane & j) == 0;
                bool up = (lane & k) == 0;
                int mn = other < v ? other : v;
                int mx = other < v ? v : other;
                v = up ? (lower ? mn : mx) : (lower ? mx : mn);
            }
        }
        if (mm > 32) {  // k=64 merge class (wave-uniform branch)
#pragma unroll
            for (int j = 32; j > 0; j >>= 1) {
                int other = __shfl_xor(v, j);
                bool lower = (lane & j) == 0;
                int mn = other < v ? other : v;
                int mx = other < v ? v : other;
                v = lower ? mn : mx;  // up == true for all lanes at k=64
            }
        }
        // pre-shifted byte offsets; lanes >= mm hold sentinels, never shuffled-from
        int sv = v << 8;
        int j = 0;
        for (; j + 16 <= mm; j += 16) {  // 4 loads (16 srcs) in flight
            int o0 = __shfl(sv, j + g) + c16;
            int o1 = __shfl(sv, j + 4 + g) + c16;
            int o2 = __shfl(sv, j + 8 + g) + c16;
            int o3 = __shfl(sv, j + 12 + g) + c16;
            uintx4 ld0 = *(const uintx4*)(ybase + (unsigned)o0);
            uintx4 ld1 = *(const uintx4*)(ybase + (unsigned)o1);
            uintx4 ld2 = *(const uintx4*)(ybase + (unsigned)o2);
            uintx4 ld3 = *(const uintx4*)(ybase + (unsigned)o3);
            ACC16(ld0) ACC16(ld1) ACC16(ld2) ACC16(ld3)
        }
        for (; j + 8 <= mm; j += 8) {
            int o0 = __shfl(sv, j + g) + c16;
            int o1 = __shfl(sv, j + 4 + g) + c16;
            uintx4 ld0 = *(const uintx4*)(ybase + (unsigned)o0);
            uintx4 ld1 = *(const uintx4*)(ybase + (unsigned)o1);
            ACC16(ld0) ACC16(ld1)
        }
        if (j < mm) {  // tail: up to 7 edges
            int i0 = j + g, i1 = j + 4 + g;
            int o0 = __shfl(sv, i0 < mm ? i0 : 0) + c16;
            int o1 = __shfl(sv, i1 < mm ? i1 : 0) + c16;
            if (i0 < mm) {
                uintx4 ld0 = *(const uintx4*)(ybase + (unsigned)o0);
                ACC16(ld0)
            }
            if (i1 < mm) {
                uintx4 ld1 = *(const uintx4*)(ybase + (unsigned)o1);
                ACC16(ld1)
            }
        }
    }
#undef ACC16

    // combine the 4 edge-slot groups (same batch, same c8)
#pragma unroll
    for (int k = 0; k < 4; ++k) {
        acc2[k].x += __shfl_xor(acc2[k].x, 16);
        acc2[k].x += __shfl_xor(acc2[k].x, 32);
        acc2[k].y += __shfl_xor(acc2[k].y, 16);
        acc2[k].y += __shfl_xor(acc2[k].y, 32);
    }

    if (g == 0) {  // 16 lanes write the full 512B row, coalesced
        float nw = rsqrtf((float)cntS[n] + 1.0f);
        const unsigned short* ys = yb + (size_t)bg * (NN * 128) + (size_t)n * 128 + c8 * 8;
        ushort8v yv = *(const ushort8v*)ys;
        floatx4 o0, o1;
        const float* bp = bias + c8 * 8;
        o0.x = nw * (acc2[0].x + bf2f((unsigned short)yv[0])) + bp[0];
        o0.y = nw * (acc2[0].y + bf2f((unsigned short)yv[1])) + bp[1];
        o0.z = nw * (acc2[1].x + bf2f((unsigned short)yv[2])) + bp[2];
        o0.w = nw * (acc2[1].y + bf2f((unsigned short)yv[3])) + bp[3];
        o1.x = nw * (acc2[2].x + bf2f((unsigned short)yv[4])) + bp[4];
        o1.y = nw * (acc2[2].y + bf2f((unsigned short)yv[5])) + bp[5];
        o1.z = nw * (acc2[3].x + bf2f((unsigned short)yv[6])) + bp[6];
        o1.w = nw * (acc2[3].y + bf2f((unsigned short)yv[7])) + bp[7];
        float* op = out + ((size_t)bg * NN + n) * 128 + c8 * 8;
        __builtin_nontemporal_store(o0, (floatx4*)op);
        __builtin_nontemporal_store(o1, (floatx4*)(op + 4));
    }
}

extern "C" void kernel_launch(void* const* d_in, const int* in_sizes, int n_in,
                              void* d_out, int out_size, void* d_ws, size_t ws_size,
                              hipStream_t stream) {
    const float* inputs = (const float*)d_in[0];   // (2, 50000, 128) fp32
    const float* W      = (const float*)d_in[1];   // (128, 128) fp32
    const float* bias   = (const float*)d_in[2];   // (1, 1, 128) fp32
    const int*   adj    = (const int*)d_in[3];     // (1600000, 2) int32
    float* out = (float*)d_out;                    // (2, 50000, 128) fp32

    const int total_rows = BB * NN;  // 100000

    char* ws = (char*)d_ws;
    size_t off = 0;
    unsigned short* y = (unsigned short*)(ws + off);
    off += (size_t)BB * NN * DD * sizeof(unsigned short);          // 25.6 MB
    unsigned short* csr_src = (unsigned short*)(ws + off);
    off += (size_t)NN * SLOTS * sizeof(unsigned short);            // 9.6 MB
    unsigned int* cnt = (unsigned int*)(ws + off);                 // cntD | cntS
    off += (size_t)2 * NN * sizeof(unsigned int);                  // 400 KB
    unsigned int* cntD = cnt;
    unsigned int* cntS = cnt + NN;

    hipMemsetAsync(cnt, 0, (size_t)2 * NN * sizeof(unsigned int), stream);
    scatter_atomic_kernel<<<EE / 2 / 256, 256, 0, stream>>>((const int4*)adj, cntD, cntS,
                                                            csr_src);
    gemm_mfma_kernel<<<(total_rows + 255) / 256, 1024, 0, stream>>>(inputs, W, cntS, y,
                                                                    total_rows);
    aggregate_kernel<<<NN / 4 * BB, 256, 0, stream>>>(y, csr_src, cntD, cntS, bias, out);
}

// Round 11
// 250.919 us; speedup vs baseline: 1.4190x; 1.4190x over previous
//
#include <hip/hip_runtime.h>
#include <hip/hip_bf16.h>

// GraphConv on MI355X — zero global atomics, u8 counting-sort into FIXED-STRIDE
// CSR (96 slots/node), batch-per-XCD plane split in aggregate.
//   y[b][n][:] = bf16(nw[n] * (inputs[b,n] @ W))    (MFMA 16x16x32 bf16)
//   out[b,n,:] = nw[n]*(y[b][n] + sum_{e:dst=n} y[b][src_e]) + bias
// R19: R10's atomic scatter REFUTED (151us alone: WRITE 142MB write-allocate
// pathology on random u16 stores + serialized atomic chains at 12.5% HBM).
// Full revert to R9 counting-sort structure. ABLATION: the aggregate bitonic
// src-sort (R2->R3 measured cost ~13us of serial swizzle chains) is deleted —
// counting-sort CSR order is already deterministic (chunk-major, rank), and
// the "sorted sweep -> L2 locality" claim was never isolated. If FETCH holds
// ~293MB the sort was pure overhead; if it balloons >360MB the claim is real
// and the sort returns next round.

#define NN 50000
#define EE 1600000
#define DD 128
#define BB 2
#define NB 128        // histogram blocks (edge chunks); counts Poisson(0.25) << 255
#define CHUNK 12500   // EE / NB
#define HS 50000      // hist row stride (u8 elems), %4==0
#define HW4 (HS / 4)  // row stride in u32 words
#define SLOTS 96      // fixed csr row stride (u16 elems); max deg ~60 << 96

typedef __attribute__((ext_vector_type(8))) short short8;
typedef __attribute__((ext_vector_type(8))) unsigned short ushort8v;
typedef __attribute__((ext_vector_type(4))) float floatx4;
typedef __attribute__((ext_vector_type(2))) float floatx2;
typedef __attribute__((ext_vector_type(4))) unsigned int uintx4;

__device__ inline unsigned short f2bf(float f) {  // RNE fp32 -> bf16 bits
    unsigned u = __float_as_uint(f);
    unsigned r = u + 0x7fffu + ((u >> 16) & 1u);
    return (unsigned short)(r >> 16);
}
__device__ inline float bf2f(unsigned short h) {
    return __uint_as_float(((unsigned)h) << 16);
}

// ---------------- per-block full-range u8-packed histograms ----------------
// grid (NB, 2): y=0 -> dst counts + ranks; y=1 -> src counts. 256 blocks = 1/CU.
__global__ __launch_bounds__(1024) void phist_kernel(const int4* __restrict__ adj2,
                                                     unsigned int* __restrict__ histD32,
                                                     unsigned int* __restrict__ histS32,
                                                     unsigned char* __restrict__ rank) {
    __shared__ unsigned int h[HW4];  // 50 KB
    int b = blockIdx.x;
    int p0 = b * (CHUNK / 2);  // pair index base

    for (int i = threadIdx.x; i < HW4; i += 1024) h[i] = 0;
    __syncthreads();
    if (blockIdx.y == 0) {
        // ---- dst: counts + ranks ----
        for (int i = threadIdx.x; i < CHUNK / 2; i += 1024) {
            int4 two = adj2[p0 + i];  // edges (x,y) and (z,w): (src,dst)
            unsigned ka = (unsigned)two.y, kb = (unsigned)two.w;
            unsigned sha = (ka & 3u) << 3, shb = (kb & 3u) << 3;
            unsigned olda = atomicAdd(&h[ka >> 2], 1u << sha);
            unsigned oldb = atomicAdd(&h[kb >> 2], 1u << shb);
            unsigned r0 = (olda >> sha) & 0xffu;
            unsigned r1 = (oldb >> shb) & 0xffu;
            int e = b * CHUNK + 2 * i;
            *(unsigned short*)(rank + e) = (unsigned short)(r0 | (r1 << 8));
        }
        __syncthreads();
        for (int i = threadIdx.x; i < HW4; i += 1024) histD32[(size_t)b * HW4 + i] = h[i];
    } else {
        // ---- src: counts only ----
        for (int i = threadIdx.x; i < CHUNK / 2; i += 1024) {
            int4 two = adj2[p0 + i];
            unsigned ka = (unsigned)two.x, kb = (unsigned)two.z;
            atomicAdd(&h[ka >> 2], 1u << ((ka & 3u) << 3));
            atomicAdd(&h[kb >> 2], 1u << ((kb & 3u) << 3));
        }
        __syncthreads();
        for (int i = threadIdx.x; i < HW4; i += 1024) histS32[(size_t)b * HW4 + i] = h[i];
    }
}

// ---------------- reduce: prefix-over-blocks (u8, in place) + deg8 + node_w ----------------
// 1 thread per key, 196 blocks.
__global__ __launch_bounds__(256) void reduce_hist_kernel(unsigned char* __restrict__ histD,
                                                          const unsigned char* __restrict__ histS,
                                                          unsigned char* __restrict__ deg8,
                                                          float* __restrict__ node_w) {
    int k = blockIdx.x * 256 + threadIdx.x;
    if (k >= NN) return;
    unsigned run = 0;
#pragma unroll 8
    for (int b = 0; b < NB; ++b) {
        size_t idx = (size_t)b * HS + k;
        unsigned c = histD[idx];
        histD[idx] = (unsigned char)run;
        run += c;
    }
    deg8[k] = (unsigned char)run;

    unsigned s = 0;
#pragma unroll 8
    for (int b = 0; b < NB; ++b) s += histS[(size_t)b * HS + k];
    node_w[k] = rsqrtf((float)s + 1.0f);
}

// ---------------- atomic-free scatter into fixed-stride CSR (u16 payload) ----------------
// pos = dst*SLOTS + chunk_base(histD) + rank — deterministic order.
__global__ __launch_bounds__(256) void scatter_kernel(const int4* __restrict__ adj2,
                                                      const unsigned short* __restrict__ rank16,
                                                      const unsigned char* __restrict__ histD,
                                                      unsigned short* __restrict__ csr_src) {
    int i = blockIdx.x * blockDim.x + threadIdx.x;  // pair index, grid == EE/2
    int4 two = adj2[i];
    unsigned rr = rank16[i];
    int e = 2 * i;
    int b = e / CHUNK;
    int posA = two.y * SLOTS + (int)histD[(size_t)b * HS + two.y] + (int)(rr & 0xffu);
    int posB = two.w * SLOTS + (int)histD[(size_t)b * HS + two.w] + (int)(rr >> 8);
    csr_src[posA] = (unsigned short)two.x;
    csr_src[posB] = (unsigned short)two.z;
}

// ---------------- y = bf16(nw * (inputs @ W)), plane layout [b][n][128] ----------------
#define WT_STRIDE 136
__global__ __launch_bounds__(1024) void gemm_mfma_kernel(const float* __restrict__ in,
                                                         const float* __restrict__ W,
                                                         const float* __restrict__ node_w,
                                                         unsigned short* __restrict__ y,
                                                         int total_rows) {
    __shared__ unsigned short wt[128 * WT_STRIDE];  // W^T as bf16, ~34 KB
    for (int i = threadIdx.x; i < 128 * 128; i += 1024) {
        int d = i >> 7, o = i & 127;
        wt[o * WT_STRIDE + d] = f2bf(W[i]);
    }
    __syncthreads();

    int wave = threadIdx.x >> 6;  // 0..15
    int lane = threadIdx.x & 63;
    int m = lane & 15;
    int quad = lane >> 4;
    int rt = (blockIdx.x * 16 + wave) * 16;
    if (rt >= total_rows) return;

    short8 a[4];
    const float* arow = in + (size_t)(rt + m) * 128;
#pragma unroll
    for (int kt = 0; kt < 4; ++kt) {
        int k0 = kt * 32 + quad * 8;
        float4 f0 = *(const float4*)(arow + k0);
        float4 f1 = *(const float4*)(arow + k0 + 4);
        short8 av;
        av[0] = (short)f2bf(f0.x); av[1] = (short)f2bf(f0.y);
        av[2] = (short)f2bf(f0.z); av[3] = (short)f2bf(f0.w);
        av[4] = (short)f2bf(f1.x); av[5] = (short)f2bf(f1.y);
        av[6] = (short)f2bf(f1.z); av[7] = (short)f2bf(f1.w);
        a[kt] = av;
    }

    float nw[4];
#pragma unroll
    for (int r = 0; r < 4; ++r) {
        int row = rt + quad * 4 + r;
        int n = row - (row >= NN ? NN : 0);
        nw[r] = node_w[n];
    }

#pragma unroll
    for (int ct = 0; ct < 8; ++ct) {
        floatx4 acc = {0.f, 0.f, 0.f, 0.f};
#pragma unroll
        for (int kt = 0; kt < 4; ++kt) {
            const short8* bp =
                (const short8*)&wt[(ct * 16 + m) * WT_STRIDE + kt * 32 + quad * 8];
            acc = __builtin_amdgcn_mfma_f32_16x16x32_bf16(a[kt], *bp, acc, 0, 0, 0);
        }
        int col = ct * 16 + m;
#pragma unroll
        for (int r = 0; r < 4; ++r) {
            int row = rt + quad * 4 + r;
            y[(size_t)row * 128 + col] = f2bf(nw[r] * acc[r]);
        }
    }
}

// ---------------- aggregation: 1 wave per (node,batch), unsorted CSR gathers ----------------
// blk%8 -> XCD: batch = (blk%8)>>2 -> each XCD sweeps ONE 12.8MB y-plane
// (R6: dropping this costs +59MB FETCH, +7us). NO bitonic sort this round
// (ablation): CSR order is deterministic; the sort's serial swizzle chains
// cost ~13us (R2->R3) and its locality value was never isolated.
// 4 dwordx4 gathers in flight; nt stores; launch_bounds(256,8).
__global__ __launch_bounds__(256, 8) void aggregate_kernel(
    const unsigned short* __restrict__ yb, const unsigned short* __restrict__ csr_src,
    const unsigned char* __restrict__ deg8, const float* __restrict__ node_w,
    const float* __restrict__ bias, float* __restrict__ out) {
    int wave = threadIdx.x >> 6;
    int lane = threadIdx.x & 63;
    unsigned blk = blockIdx.x;                     // [0, 25000)
    int xcd = (int)(blk & 7u);
    int bg = xcd >> 2;                             // batch
    int nbid = (int)(blk >> 3) * 4 + (xcd & 3);    // [0, 12500)
    int n = nbid * 4 + wave;

    int g = lane >> 4;
    int c8 = lane & 15;
    int c16 = c8 * 16;
    const char* ybase = (const char*)yb + (size_t)bg * (NN * 128 * 2);

    int start = n * SLOTS;                         // wave-uniform, scalar
    int cnt = __builtin_amdgcn_readfirstlane((int)deg8[n]);

    floatx2 acc2[4];
#pragma unroll
    for (int k = 0; k < 4; ++k) acc2[k] = (floatx2){0.f, 0.f};

#define ACC16(LD)                                                       \
    {                                                                   \
        _Pragma("unroll") for (int d = 0; d < 4; ++d) {                 \
            floatx2 v2;                                                 \
            v2.x = __uint_as_float((LD)[d] << 16);                      \
            v2.y = __uint_as_float((LD)[d] & 0xffff0000u);              \
            acc2[d] += v2;                                              \
        }                                                               \
    }

    for (int base = 0; base < cnt; base += 64) {
        int mm = cnt - base; if (mm > 64) mm = 64;
        // load tile in CSR order (deterministic), pre-shift to byte offsets
        int sv = 0;
        if (lane < mm) sv = ((int)csr_src[start + base + lane]) << 8;
        int j = 0;
        for (; j + 16 <= mm; j += 16) {  // 4 loads (16 srcs) in flight
            int o0 = __shfl(sv, j + g) + c16;
            int o1 = __shfl(sv, j + 4 + g) + c16;
            int o2 = __shfl(sv, j + 8 + g) + c16;
            int o3 = __shfl(sv, j + 12 + g) + c16;
            uintx4 ld0 = *(const uintx4*)(ybase + (unsigned)o0);
            uintx4 ld1 = *(const uintx4*)(ybase + (unsigned)o1);
            uintx4 ld2 = *(const uintx4*)(ybase + (unsigned)o2);
            uintx4 ld3 = *(const uintx4*)(ybase + (unsigned)o3);
            ACC16(ld0) ACC16(ld1) ACC16(ld2) ACC16(ld3)
        }
        for (; j + 8 <= mm; j += 8) {
            int o0 = __shfl(sv, j + g) + c16;
            int o1 = __shfl(sv, j + 4 + g) + c16;
            uintx4 ld0 = *(const uintx4*)(ybase + (unsigned)o0);
            uintx4 ld1 = *(const uintx4*)(ybase + (unsigned)o1);
            ACC16(ld0) ACC16(ld1)
        }
        if (j < mm) {  // tail: up to 7 edges
            int i0 = j + g, i1 = j + 4 + g;
            int o0 = __shfl(sv, i0 < mm ? i0 : 0) + c16;
            int o1 = __shfl(sv, i1 < mm ? i1 : 0) + c16;
            if (i0 < mm) {
                uintx4 ld0 = *(const uintx4*)(ybase + (unsigned)o0);
                ACC16(ld0)
            }
            if (i1 < mm) {
                uintx4 ld1 = *(const uintx4*)(ybase + (unsigned)o1);
                ACC16(ld1)
            }
        }
    }
#undef ACC16

    // combine the 4 edge-slot groups (same batch, same c8)
#pragma unroll
    for (int k = 0; k < 4; ++k) {
        acc2[k].x += __shfl_xor(acc2[k].x, 16);
        acc2[k].x += __shfl_xor(acc2[k].x, 32);
        acc2[k].y += __shfl_xor(acc2[k].y, 16);
        acc2[k].y += __shfl_xor(acc2[k].y, 32);
    }

    if (g == 0) {  // 16 lanes write the full 512B row, coalesced
        float nw = node_w[n];
        const unsigned short* ys = yb + (size_t)bg * (NN * 128) + (size_t)n * 128 + c8 * 8;
        ushort8v yv = *(const ushort8v*)ys;
        floatx4 o0, o1;
        const float* bp = bias + c8 * 8;
        o0.x = nw * (acc2[0].x + bf2f((unsigned short)yv[0])) + bp[0];
        o0.y = nw * (acc2[0].y + bf2f((unsigned short)yv[1])) + bp[1];
        o0.z = nw * (acc2[1].x + bf2f((unsigned short)yv[2])) + bp[2];
        o0.w = nw * (acc2[1].y + bf2f((unsigned short)yv[3])) + bp[3];
        o1.x = nw * (acc2[2].x + bf2f((unsigned short)yv[4])) + bp[4];
        o1.y = nw * (acc2[2].y + bf2f((unsigned short)yv[5])) + bp[5];
        o1.z = nw * (acc2[3].x + bf2f((unsigned short)yv[6])) + bp[6];
        o1.w = nw * (acc2[3].y + bf2f((unsigned short)yv[7])) + bp[7];
        float* op = out + ((size_t)bg * NN + n) * 128 + c8 * 8;
        __builtin_nontemporal_store(o0, (floatx4*)op);
        __builtin_nontemporal_store(o1, (floatx4*)(op + 4));
    }
}

extern "C" void kernel_launch(void* const* d_in, const int* in_sizes, int n_in,
                              void* d_out, int out_size, void* d_ws, size_t ws_size,
                              hipStream_t stream) {
    const float* inputs = (const float*)d_in[0];   // (2, 50000, 128) fp32
    const float* W      = (const float*)d_in[1];   // (128, 128) fp32
    const float* bias   = (const float*)d_in[2];   // (1, 1, 128) fp32
    const int*   adj    = (const int*)d_in[3];     // (1600000, 2) int32
    float* out = (float*)d_out;                    // (2, 50000, 128) fp32

    const int total_rows = BB * NN;  // 100000

    char* ws = (char*)d_ws;
    size_t off = 0;
    unsigned short* y = (unsigned short*)(ws + off);
    off += (size_t)BB * NN * DD * sizeof(unsigned short);          // 25.6 MB
    unsigned char* histD = (unsigned char*)(ws + off);
    off += (size_t)NB * HS;                                        // 6.4 MB
    // csr (9.6 MB); histS aliases its first 6.4 MB — histS is dead after
    // reduce_hist, before scatter writes csr.
    unsigned short* csr_src = (unsigned short*)(ws + off);
    unsigned char* histS = (unsigned char*)(ws + off);
    off += (size_t)NN * SLOTS * sizeof(unsigned short);            // 9.6 MB
    unsigned char* rank = (unsigned char*)(ws + off);
    off += (size_t)EE;                                             // 1.6 MB
    unsigned char* deg8 = (unsigned char*)(ws + off);
    off += (size_t)((NN + 255) & ~255);                            // 50 KB
    float* node_w = (float*)(ws + off);  off += (size_t)NN * sizeof(float);

    dim3 hgrid(NB, 2);
    phist_kernel<<<hgrid, 1024, 0, stream>>>((const int4*)adj, (unsigned int*)histD,
                                             (unsigned int*)histS, rank);
    reduce_hist_kernel<<<(NN + 255) / 256, 256, 0, stream>>>(histD, histS, deg8, node_w);
    scatter_kernel<<<EE / 2 / 256, 256, 0, stream>>>((const int4*)adj,
                                                     (const unsigned short*)rank, histD,
                                                     csr_src);
    gemm_mfma_kernel<<<(total_rows + 255) / 256, 1024, 0, stream>>>(inputs, W, node_w, y,
                                                                    total_rows);
    aggregate_kernel<<<NN / 4 * BB, 256, 0, stream>>>(y, csr_src, deg8, node_w, bias, out);
}

// Round 12
// 248.504 us; speedup vs baseline: 1.4328x; 1.0097x over previous
//
#include <hip/hip_runtime.h>
#include <hip/hip_bf16.h>

// GraphConv on MI355X — zero global atomics, u8 counting-sort into FIXED-STRIDE
// CSR (96 slots/node), batch-per-XCD plane split in aggregate.
//   y[b][n][:] = bf16(nw[n] * (inputs[b,n] @ W))    (MFMA 16x16x32 bf16)
//   out[b,n,:] = nw[n]*(y[b][n] + sum_{e:dst=n} y[b][src_e]) + bias
// R20: (a) aggregate MLP 4 -> 6 gathers in flight (24-edge main batch).
//     R11 freed VGPR to 28; +8 VGPR -> 36 -> 7 waves/SIMD (-12.5% TLP vs
//     R2's catastrophic -37.5%) for +50% per-wave MLP. launch_bounds(256,7).
//     csr tile load now unconditional (lanes >= mm never shuffled-from).
// (b) phist src pass: 64 blocks x 2 chunks (counts Poisson(0.5) << 255) ->
//     histS writes 6.4 -> 3.2MB, reduce's histS sweep 128 -> 64 rows.

#define NN 50000
#define EE 1600000
#define DD 128
#define BB 2
#define NB 128        // dst histogram blocks (edge chunks)
#define NBS 64        // src histogram blocks (2 chunks each)
#define CHUNK 12500   // EE / NB
#define HS 50000      // hist row stride (u8 elems), %4==0
#define HW4 (HS / 4)  // row stride in u32 words
#define SLOTS 96      // fixed csr row stride (u16 elems); max deg ~60 << 96

typedef __attribute__((ext_vector_type(8))) short short8;
typedef __attribute__((ext_vector_type(8))) unsigned short ushort8v;
typedef __attribute__((ext_vector_type(4))) float floatx4;
typedef __attribute__((ext_vector_type(2))) float floatx2;
typedef __attribute__((ext_vector_type(4))) unsigned int uintx4;

__device__ inline unsigned short f2bf(float f) {  // RNE fp32 -> bf16 bits
    unsigned u = __float_as_uint(f);
    unsigned r = u + 0x7fffu + ((u >> 16) & 1u);
    return (unsigned short)(r >> 16);
}
__device__ inline float bf2f(unsigned short h) {
    return __uint_as_float(((unsigned)h) << 16);
}

// ---------------- per-block full-range u8-packed histograms ----------------
// grid (NB, 2): y=0 -> dst counts + ranks (128 blocks); y=1 -> src counts
// (64 blocks x 2 chunks; rest idle).
__global__ __launch_bounds__(1024) void phist_kernel(const int4* __restrict__ adj2,
                                                     unsigned int* __restrict__ histD32,
                                                     unsigned int* __restrict__ histS32,
                                                     unsigned char* __restrict__ rank) {
    int b = blockIdx.x;
    if (blockIdx.y == 1 && b >= NBS) return;
    __shared__ unsigned int h[HW4];  // 50 KB

    for (int i = threadIdx.x; i < HW4; i += 1024) h[i] = 0;
    __syncthreads();
    if (blockIdx.y == 0) {
        // ---- dst: counts + ranks ----
        int p0 = b * (CHUNK / 2);  // pair index base
        for (int i = threadIdx.x; i < CHUNK / 2; i += 1024) {
            int4 two = adj2[p0 + i];  // edges (x,y) and (z,w): (src,dst)
            unsigned ka = (unsigned)two.y, kb = (unsigned)two.w;
            unsigned sha = (ka & 3u) << 3, shb = (kb & 3u) << 3;
            unsigned olda = atomicAdd(&h[ka >> 2], 1u << sha);
            unsigned oldb = atomicAdd(&h[kb >> 2], 1u << shb);
            unsigned r0 = (olda >> sha) & 0xffu;
            unsigned r1 = (oldb >> shb) & 0xffu;
            int e = b * CHUNK + 2 * i;
            *(unsigned short*)(rank + e) = (unsigned short)(r0 | (r1 << 8));
        }
        __syncthreads();
        for (int i = threadIdx.x; i < HW4; i += 1024) histD32[(size_t)b * HW4 + i] = h[i];
    } else {
        // ---- src: counts only, 2 chunks per block ----
        int p0 = b * CHUNK;  // = (2b)*(CHUNK/2), covers chunks 2b and 2b+1
        for (int i = threadIdx.x; i < CHUNK; i += 1024) {
            int4 two = adj2[p0 + i];
            unsigned ka = (unsigned)two.x, kb = (unsigned)two.z;
            atomicAdd(&h[ka >> 2], 1u << ((ka & 3u) << 3));
            atomicAdd(&h[kb >> 2], 1u << ((kb & 3u) << 3));
        }
        __syncthreads();
        for (int i = threadIdx.x; i < HW4; i += 1024) histS32[(size_t)b * HW4 + i] = h[i];
    }
}

// ---------------- reduce: prefix-over-blocks (u8, in place) + deg8 + node_w ----------------
// 1 thread per key, 196 blocks.
__global__ __launch_bounds__(256) void reduce_hist_kernel(unsigned char* __restrict__ histD,
                                                          const unsigned char* __restrict__ histS,
                                                          unsigned char* __restrict__ deg8,
                                                          float* __restrict__ node_w) {
    int k = blockIdx.x * 256 + threadIdx.x;
    if (k >= NN) return;
    unsigned run = 0;
#pragma unroll 8
    for (int b = 0; b < NB; ++b) {
        size_t idx = (size_t)b * HS + k;
        unsigned c = histD[idx];
        histD[idx] = (unsigned char)run;
        run += c;
    }
    deg8[k] = (unsigned char)run;

    unsigned s = 0;
#pragma unroll 8
    for (int b = 0; b < NBS; ++b) s += histS[(size_t)b * HS + k];
    node_w[k] = rsqrtf((float)s + 1.0f);
}

// ---------------- atomic-free scatter into fixed-stride CSR (u16 payload) ----------------
// pos = dst*SLOTS + chunk_base(histD) + rank — deterministic order.
__global__ __launch_bounds__(256) void scatter_kernel(const int4* __restrict__ adj2,
                                                      const unsigned short* __restrict__ rank16,
                                                      const unsigned char* __restrict__ histD,
                                                      unsigned short* __restrict__ csr_src) {
    int i = blockIdx.x * blockDim.x + threadIdx.x;  // pair index, grid == EE/2
    int4 two = adj2[i];
    unsigned rr = rank16[i];
    int e = 2 * i;
    int b = e / CHUNK;
    int posA = two.y * SLOTS + (int)histD[(size_t)b * HS + two.y] + (int)(rr & 0xffu);
    int posB = two.w * SLOTS + (int)histD[(size_t)b * HS + two.w] + (int)(rr >> 8);
    csr_src[posA] = (unsigned short)two.x;
    csr_src[posB] = (unsigned short)two.z;
}

// ---------------- y = bf16(nw * (inputs @ W)), plane layout [b][n][128] ----------------
#define WT_STRIDE 136
__global__ __launch_bounds__(1024) void gemm_mfma_kernel(const float* __restrict__ in,
                                                         const float* __restrict__ W,
                                                         const float* __restrict__ node_w,
                                                         unsigned short* __restrict__ y,
                                                         int total_rows) {
    __shared__ unsigned short wt[128 * WT_STRIDE];  // W^T as bf16, ~34 KB
    for (int i = threadIdx.x; i < 128 * 128; i += 1024) {
        int d = i >> 7, o = i & 127;
        wt[o * WT_STRIDE + d] = f2bf(W[i]);
    }
    __syncthreads();

    int wave = threadIdx.x >> 6;  // 0..15
    int lane = threadIdx.x & 63;
    int m = lane & 15;
    int quad = lane >> 4;
    int rt = (blockIdx.x * 16 + wave) * 16;
    if (rt >= total_rows) return;

    short8 a[4];
    const float* arow = in + (size_t)(rt + m) * 128;
#pragma unroll
    for (int kt = 0; kt < 4; ++kt) {
        int k0 = kt * 32 + quad * 8;
        float4 f0 = *(const float4*)(arow + k0);
        float4 f1 = *(const float4*)(arow + k0 + 4);
        short8 av;
        av[0] = (short)f2bf(f0.x); av[1] = (short)f2bf(f0.y);
        av[2] = (short)f2bf(f0.z); av[3] = (short)f2bf(f0.w);
        av[4] = (short)f2bf(f1.x); av[5] = (short)f2bf(f1.y);
        av[6] = (short)f2bf(f1.z); av[7] = (short)f2bf(f1.w);
        a[kt] = av;
    }

    float nw[4];
#pragma unroll
    for (int r = 0; r < 4; ++r) {
        int row = rt + quad * 4 + r;
        int n = row - (row >= NN ? NN : 0);
        nw[r] = node_w[n];
    }

#pragma unroll
    for (int ct = 0; ct < 8; ++ct) {
        floatx4 acc = {0.f, 0.f, 0.f, 0.f};
#pragma unroll
        for (int kt = 0; kt < 4; ++kt) {
            const short8* bp =
                (const short8*)&wt[(ct * 16 + m) * WT_STRIDE + kt * 32 + quad * 8];
            acc = __builtin_amdgcn_mfma_f32_16x16x32_bf16(a[kt], *bp, acc, 0, 0, 0);
        }
        int col = ct * 16 + m;
#pragma unroll
        for (int r = 0; r < 4; ++r) {
            int row = rt + quad * 4 + r;
            y[(size_t)row * 128 + col] = f2bf(nw[r] * acc[r]);
        }
    }
}

// ---------------- aggregation: 1 wave per (node,batch), unsorted CSR gathers ----------------
// blk%8 -> XCD: batch = (blk%8)>>2 -> each XCD sweeps ONE 12.8MB y-plane
// (R6: dropping this costs +59MB FETCH, +7us). No sort (R11 ablation: the
// bitonic was pure overhead, -8.4us, FETCH unchanged). R12: 6 gathers in
// flight (24-edge main batch) at launch_bounds(256,7): VGPR ~36 -> 7 waves/
// SIMD; in-flight +31% vs R11's 4-deep/8-wave. csr tile loaded
// unconditionally (lanes >= mm never shuffled-from). nt stores.
__global__ __launch_bounds__(256, 7) void aggregate_kernel(
    const unsigned short* __restrict__ yb, const unsigned short* __restrict__ csr_src,
    const unsigned char* __restrict__ deg8, const float* __restrict__ node_w,
    const float* __restrict__ bias, float* __restrict__ out) {
    int wave = threadIdx.x >> 6;
    int lane = threadIdx.x & 63;
    unsigned blk = blockIdx.x;                     // [0, 25000)
    int xcd = (int)(blk & 7u);
    int bg = xcd >> 2;                             // batch
    int nbid = (int)(blk >> 3) * 4 + (xcd & 3);    // [0, 12500)
    int n = nbid * 4 + wave;

    int g = lane >> 4;
    int c8 = lane & 15;
    int c16 = c8 * 16;
    const char* ybase = (const char*)yb + (size_t)bg * (NN * 128 * 2);

    int start = n * SLOTS;                         // wave-uniform, scalar
    int cnt = __builtin_amdgcn_readfirstlane((int)deg8[n]);

    floatx2 acc2[4];
#pragma unroll
    for (int k = 0; k < 4; ++k) acc2[k] = (floatx2){0.f, 0.f};

#define ACC16(LD)                                                       \
    {                                                                   \
        _Pragma("unroll") for (int d = 0; d < 4; ++d) {                 \
            floatx2 v2;                                                 \
            v2.x = __uint_as_float((LD)[d] << 16);                      \
            v2.y = __uint_as_float((LD)[d] & 0xffff0000u);              \
            acc2[d] += v2;                                              \
        }                                                               \
    }

    for (int base = 0; base < cnt; base += 64) {
        int mm = cnt - base; if (mm > 64) mm = 64;
        // load tile unconditionally (lanes >= mm hold garbage, never shuffled-from;
        // 96-slot rows + trailing workspace keep the over-read in bounds)
        int sv = ((int)csr_src[start + base + lane]) << 8;
        int j = 0;
        for (; j + 24 <= mm; j += 24) {  // 6 loads (24 srcs) in flight
            int o0 = __shfl(sv, j + g) + c16;
            int o1 = __shfl(sv, j + 4 + g) + c16;
            int o2 = __shfl(sv, j + 8 + g) + c16;
            int o3 = __shfl(sv, j + 12 + g) + c16;
            int o4 = __shfl(sv, j + 16 + g) + c16;
            int o5 = __shfl(sv, j + 20 + g) + c16;
            uintx4 ld0 = *(const uintx4*)(ybase + (unsigned)o0);
            uintx4 ld1 = *(const uintx4*)(ybase + (unsigned)o1);
            uintx4 ld2 = *(const uintx4*)(ybase + (unsigned)o2);
            uintx4 ld3 = *(const uintx4*)(ybase + (unsigned)o3);
            uintx4 ld4 = *(const uintx4*)(ybase + (unsigned)o4);
            uintx4 ld5 = *(const uintx4*)(ybase + (unsigned)o5);
            ACC16(ld0) ACC16(ld1) ACC16(ld2) ACC16(ld3) ACC16(ld4) ACC16(ld5)
        }
        for (; j + 16 <= mm; j += 16) {  // 4 loads
            int o0 = __shfl(sv, j + g) + c16;
            int o1 = __shfl(sv, j + 4 + g) + c16;
            int o2 = __shfl(sv, j + 8 + g) + c16;
            int o3 = __shfl(sv, j + 12 + g) + c16;
            uintx4 ld0 = *(const uintx4*)(ybase + (unsigned)o0);
            uintx4 ld1 = *(const uintx4*)(ybase + (unsigned)o1);
            uintx4 ld2 = *(const uintx4*)(ybase + (unsigned)o2);
            uintx4 ld3 = *(const uintx4*)(ybase + (unsigned)o3);
            ACC16(ld0) ACC16(ld1) ACC16(ld2) ACC16(ld3)
        }
        for (; j + 8 <= mm; j += 8) {  // 2 loads
            int o0 = __shfl(sv, j + g) + c16;
            int o1 = __shfl(sv, j + 4 + g) + c16;
            uintx4 ld0 = *(const uintx4*)(ybase + (unsigned)o0);
            uintx4 ld1 = *(const uintx4*)(ybase + (unsigned)o1);
            ACC16(ld0) ACC16(ld1)
        }
        if (j < mm) {  // tail: up to 7 edges
            int i0 = j + g, i1 = j + 4 + g;
            int o0 = __shfl(sv, i0 < mm ? i0 : 0) + c16;
            int o1 = __shfl(sv, i1 < mm ? i1 : 0) + c16;
            if (i0 < mm) {
                uintx4 ld0 = *(const uintx4*)(ybase + (unsigned)o0);
                ACC16(ld0)
            }
            if (i1 < mm) {
                uintx4 ld1 = *(const uintx4*)(ybase + (unsigned)o1);
                ACC16(ld1)
            }
        }
    }
#undef ACC16

    // combine the 4 edge-slot groups (same batch, same c8)
#pragma unroll
    for (int k = 0; k < 4; ++k) {
        acc2[k].x += __shfl_xor(acc2[k].x, 16);
        acc2[k].x += __shfl_xor(acc2[k].x, 32);
        acc2[k].y += __shfl_xor(acc2[k].y, 16);
        acc2[k].y += __shfl_xor(acc2[k].y, 32);
    }

    if (g == 0) {  // 16 lanes write the full 512B row, coalesced
        float nw = node_w[n];
        const unsigned short* ys = yb + (size_t)bg * (NN * 128) + (size_t)n * 128 + c8 * 8;
        ushort8v yv = *(const ushort8v*)ys;
        floatx4 o0, o1;
        const float* bp = bias + c8 * 8;
        o0.x = nw * (acc2[0].x + bf2f((unsigned short)yv[0])) + bp[0];
        o0.y = nw * (acc2[0].y + bf2f((unsigned short)yv[1])) + bp[1];
        o0.z = nw * (acc2[1].x + bf2f((unsigned short)yv[2])) + bp[2];
        o0.w = nw * (acc2[1].y + bf2f((unsigned short)yv[3])) + bp[3];
        o1.x = nw * (acc2[2].x + bf2f((unsigned short)yv[4])) + bp[4];
        o1.y = nw * (acc2[2].y + bf2f((unsigned short)yv[5])) + bp[5];
        o1.z = nw * (acc2[3].x + bf2f((unsigned short)yv[6])) + bp[6];
        o1.w = nw * (acc2[3].y + bf2f((unsigned short)yv[7])) + bp[7];
        float* op = out + ((size_t)bg * NN + n) * 128 + c8 * 8;
        __builtin_nontemporal_store(o0, (floatx4*)op);
        __builtin_nontemporal_store(o1, (floatx4*)(op + 4));
    }
}

extern "C" void kernel_launch(void* const* d_in, const int* in_sizes, int n_in,
                              void* d_out, int out_size, void* d_ws, size_t ws_size,
                              hipStream_t stream) {
    const float* inputs = (const float*)d_in[0];   // (2, 50000, 128) fp32
    const float* W      = (const float*)d_in[1];   // (128, 128) fp32
    const float* bias   = (const float*)d_in[2];   // (1, 1, 128) fp32
    const int*   adj    = (const int*)d_in[3];     // (1600000, 2) int32
    float* out = (float*)d_out;                    // (2, 50000, 128) fp32

    const int total_rows = BB * NN;  // 100000

    char* ws = (char*)d_ws;
    size_t off = 0;
    unsigned short* y = (unsigned short*)(ws + off);
    off += (size_t)BB * NN * DD * sizeof(unsigned short);          // 25.6 MB
    unsigned char* histD = (unsigned char*)(ws + off);
    off += (size_t)NB * HS;                                        // 6.4 MB
    // csr (9.6 MB); histS aliases its first 3.2 MB — histS is dead after
    // reduce_hist, before scatter writes csr.
    unsigned short* csr_src = (unsigned short*)(ws + off);
    unsigned char* histS = (unsigned char*)(ws + off);
    off += (size_t)NN * SLOTS * sizeof(unsigned short);            // 9.6 MB
    unsigned char* rank = (unsigned char*)(ws + off);
    off += (size_t)EE;                                             // 1.6 MB
    unsigned char* deg8 = (unsigned char*)(ws + off);
    off += (size_t)((NN + 255) & ~255);                            // 50 KB
    float* node_w = (float*)(ws + off);  off += (size_t)NN * sizeof(float);

    dim3 hgrid(NB, 2);
    phist_kernel<<<hgrid, 1024, 0, stream>>>((const int4*)adj, (unsigned int*)histD,
                                             (unsigned int*)histS, rank);
    reduce_hist_kernel<<<(NN + 255) / 256, 256, 0, stream>>>(histD, histS, deg8, node_w);
    scatter_kernel<<<EE / 2 / 256, 256, 0, stream>>>((const int4*)adj,
                                                     (const unsigned short*)rank, histD,
                                                     csr_src);
    gemm_mfma_kernel<<<(total_rows + 255) / 256, 1024, 0, stream>>>(inputs, W, node_w, y,
                                                                    total_rows);
    aggregate_kernel<<<NN / 4 * BB, 256, 0, stream>>>(y, csr_src, deg8, node_w, bias, out);
}